// Round 6
// baseline (235.477 us; speedup 1.0000x reference)
//
#include <hip/hip_runtime.h>
#include <stdint.h>

typedef unsigned short u16;
using bf16x8 = __attribute__((ext_vector_type(8))) __bf16;
using s16x8  = __attribute__((ext_vector_type(8))) short;
using f32x4  = __attribute__((ext_vector_type(4))) float;
using f32x16 = __attribute__((ext_vector_type(16))) float;

#define SCALE_Q 0.125f   // 64^-0.5
#define LOG2E 1.44269504088896f

__device__ __forceinline__ u16 f2bf(float f) {
  union { float f; uint32_t u; } v; v.f = f;
  uint32_t u = v.u;
  return (u16)((u + 0x7FFFu + ((u >> 16) & 1)) >> 16);
}

__device__ __forceinline__ bf16x8 ld_frag(const u16* p) {
  return __builtin_bit_cast(bf16x8, *(const s16x8*)p);
}

__device__ __forceinline__ f32x4 MF(bf16x8 a, bf16x8 b, f32x4 c) {
  return __builtin_amdgcn_mfma_f32_16x16x32_bf16(a, b, c, 0, 0, 0);
}
__device__ __forceinline__ f32x16 MF32(bf16x8 a, bf16x8 b, f32x16 c) {
  return __builtin_amdgcn_mfma_f32_32x32x16_bf16(a, b, c, 0, 0, 0);
}

// async global->LDS, 16B per lane. LDS side must be wave-uniform base + lane*16.
__device__ __forceinline__ void gld16(const u16* g, u16* l) {
  __builtin_amdgcn_global_load_lds(
      (const __attribute__((address_space(1))) uint32_t*)g,
      (__attribute__((address_space(3))) uint32_t*)l, 16, 0, 0);
}

// pack two fp32 -> bf16x2 dword (a in low half)
__device__ __forceinline__ uint32_t pk_bf16(float a, float b) {
  uint32_t u0 = __builtin_bit_cast(uint32_t, a) + 0x8000u;
  uint32_t u1 = __builtin_bit_cast(uint32_t, b) + 0x8000u;
  return __builtin_amdgcn_perm(u1, u0, 0x07060302u);  // [u1.hi16 : u0.hi16]
}

// ---------------- merged prep: cvt x->bf16 (blocks 0..6143), W_qkv^T (next 1728),
// W_proj^T (next 576) ----------------
__global__ void prep_kernel(const float* __restrict__ x, u16* __restrict__ xb,
                            const float* __restrict__ Wq, u16* __restrict__ wqt,
                            const float* __restrict__ Wp, u16* __restrict__ wpt) {
  __shared__ float tile[32][33];
  int bx = blockIdx.x;
  if (bx < 6144) {
    int i = (bx * 256 + threadIdx.x) * 4;
    float4 v = *(const float4*)(x + i);
    uint2 o;
    o.x = (uint32_t)f2bf(v.x) | ((uint32_t)f2bf(v.y) << 16);
    o.y = (uint32_t)f2bf(v.z) | ((uint32_t)f2bf(v.w) << 16);
    *(uint2*)(xb + i) = o;
    return;
  }
  bx -= 6144;
  const float* in;
  u16* out;
  int C, cb, rb;
  const int R = 768;
  if (bx < 1728) { in = Wq; out = wqt; C = 2304; cb = bx % 72; rb = bx / 72; }
  else { bx -= 1728; in = Wp; out = wpt; C = 768; cb = bx % 24; rb = bx / 24; }
  int c0 = cb * 32, r0 = rb * 32;
  int tx = threadIdx.x & 31, ty = threadIdx.x >> 5;
#pragma unroll
  for (int j = 0; j < 32; j += 8)
    tile[ty + j][tx] = in[(size_t)(r0 + ty + j) * C + c0 + tx];
  __syncthreads();
#pragma unroll
  for (int j = 0; j < 32; j += 8)
    out[(size_t)(c0 + ty + j) * R + r0 + tx] = f2bf(tile[tx][ty + j]);
}

// ---------------- QKV GEMM: C[M,N] = A[M,768] * Bt[N,768]^T + bias ----------------
// 128x128 tile, BK=64, 4 waves. Blocks dtype-pure: bn 0..5 Q, 6..11 K, 12..17 V.
__global__ __launch_bounds__(256) void gemm_qkv(
    const u16* __restrict__ A, const u16* __restrict__ Bt, const float* __restrict__ bias,
    u16* __restrict__ q_out, u16* __restrict__ k_out, u16* __restrict__ v_out) {
  constexpr int K = 768;
  __shared__ __align__(16) u16 smem[17408];
  u16* sA = smem;
  u16* sB = smem + 8192;
  const int tid = threadIdx.x;
  const int lane = tid & 63, wave = tid >> 6;
  const int ml = lane & 15, kg = lane >> 4;
  const int wr = wave >> 1, wc = wave & 1;
  const int bn = blockIdx.x, bm = blockIdx.y;

  f32x4 acc[4][4] = {};
  const u16* Abase = A + (size_t)(bm * 128) * K;
  const u16* Bbase = Bt + (size_t)(bn * 128) * K;

  for (int k0 = 0; k0 < K; k0 += 64) {
#pragma unroll
    for (int p = 0; p < 4; p++) {
      int q = p * 256 + tid;
      int r = q >> 3, s = q & 7, c = s ^ (r & 7);
      gld16(Abase + (size_t)r * K + k0 + c * 8, sA + q * 8);
      gld16(Bbase + (size_t)r * K + k0 + c * 8, sB + q * 8);
    }
    __syncthreads();
#pragma unroll
    for (int kc = 0; kc < 2; kc++) {
      bf16x8 af[4], bfr[4];
      int ac = kc * 4 + kg;
#pragma unroll
      for (int i = 0; i < 4; i++) {
        int arow = wr * 64 + i * 16 + ml;
        af[i] = ld_frag(sA + (arow * 8 + (ac ^ (arow & 7))) * 8);
        int brow = wc * 64 + i * 16 + ml;
        bfr[i] = ld_frag(sB + (brow * 8 + (ac ^ (brow & 7))) * 8);
      }
#pragma unroll
      for (int mi = 0; mi < 4; mi++)
#pragma unroll
        for (int ni = 0; ni < 4; ni++)
          acc[mi][ni] = MF(af[mi], bfr[ni], acc[mi][ni]);
    }
    __syncthreads();
  }

  // C/D layout: col = lane&15, row = (lane>>4)*4 + reg
  if (bn >= 12) {
    // ---- V block: transpose via LDS, store V^T [B,H,D,N] coalesced ----
    uint32_t* t32 = (uint32_t*)smem;  // stride 68 u32 per n_local row
#pragma unroll
    for (int ni = 0; ni < 4; ni++) {
      int n_local = wc * 64 + ni * 16 + ml;
      float bv = bias[bn * 128 + n_local];
#pragma unroll
      for (int mi = 0; mi < 4; mi++) {
        int mh = wr * 32 + mi * 8 + kg * 2;
        t32[n_local * 68 + mh]     = pk_bf16(acc[mi][ni][0] + bv, acc[mi][ni][1] + bv);
        t32[n_local * 68 + mh + 1] = pk_bf16(acc[mi][ni][2] + bv, acc[mi][ni][3] + bv);
      }
    }
    __syncthreads();
    int row = tid >> 1, seg = tid & 1;
    int dg = (bn - 12) * 128 + row;
    int h = dg >> 6, d = dg & 63;
    int bi = bm >> 4, tok0 = (bm & 15) * 128;
    u16* dst = v_out + ((size_t)(bi * 12 + h) * 64 + d) * 2048 + tok0 + seg * 64;
    const uint32_t* src = t32 + row * 68 + seg * 32;
#pragma unroll
    for (int j = 0; j < 8; j++)
      *(uint4*)(dst + j * 8) = *(const uint4*)(src + j * 4);
  } else {
    u16* dst = (bn < 6) ? q_out : k_out;
    float scl = (bn < 6) ? SCALE_Q * LOG2E : 1.0f;  // fold softmax log2e into Q
#pragma unroll
    for (int ni = 0; ni < 4; ni++) {
      int n = bn * 128 + wc * 64 + ni * 16 + ml;
      int rem = (bn < 6) ? n : n - 768;
      int h = rem >> 6, d = rem & 63;
      float bv = bias[n];
#pragma unroll
      for (int mi = 0; mi < 4; mi++) {
        int m0 = bm * 128 + wr * 64 + mi * 16 + kg * 4;
#pragma unroll
        for (int r = 0; r < 4; r++) {
          int m = m0 + r;
          int bi = m >> 11, tok = m & 2047;
          dst[(size_t)(bi * 12 + h) * 131072 + (size_t)tok * 64 + d] = f2bf((acc[mi][ni][r] + bv) * scl);
        }
      }
    }
  }
}

// ---------------- proj GEMM: 128x64 tile (768 blocks = 3/CU exact) ----------------
__global__ __launch_bounds__(256) void gemm_proj(
    const u16* __restrict__ A, const u16* __restrict__ Bt, const float* __restrict__ bias,
    float* __restrict__ c_out) {
  constexpr int K = 768;
  __shared__ __align__(16) u16 sA[128 * 64];
  __shared__ __align__(16) u16 sB[64 * 64];
  const int tid = threadIdx.x;
  const int lane = tid & 63, wave = tid >> 6;
  const int ml = lane & 15, kg = lane >> 4;
  const int bn = blockIdx.x, bm = blockIdx.y;
  f32x4 acc[2][4] = {};
  const u16* Abase = A + (size_t)(bm * 128) * K;
  const u16* Bbase = Bt + (size_t)(bn * 64) * K;

  for (int k0 = 0; k0 < K; k0 += 64) {
#pragma unroll
    for (int p = 0; p < 4; p++) {
      int q = p * 256 + tid;
      int r = q >> 3, s = q & 7, c = s ^ (r & 7);
      gld16(Abase + (size_t)r * K + k0 + c * 8, sA + q * 8);
    }
#pragma unroll
    for (int p = 0; p < 2; p++) {
      int q = p * 256 + tid;
      int r = q >> 3, s = q & 7, c = s ^ (r & 7);
      gld16(Bbase + (size_t)r * K + k0 + c * 8, sB + q * 8);
    }
    __syncthreads();
#pragma unroll
    for (int kc = 0; kc < 2; kc++) {
      int ac = kc * 4 + kg;
      bf16x8 af[2], bfr[4];
#pragma unroll
      for (int i = 0; i < 2; i++) {
        int arow = wave * 32 + i * 16 + ml;
        af[i] = ld_frag(sA + (arow * 8 + (ac ^ (arow & 7))) * 8);
      }
#pragma unroll
      for (int i = 0; i < 4; i++) {
        int brow = i * 16 + ml;
        bfr[i] = ld_frag(sB + (brow * 8 + (ac ^ (brow & 7))) * 8);
      }
#pragma unroll
      for (int mi = 0; mi < 2; mi++)
#pragma unroll
        for (int ni = 0; ni < 4; ni++)
          acc[mi][ni] = MF(af[mi], bfr[ni], acc[mi][ni]);
    }
    __syncthreads();
  }
#pragma unroll
  for (int ni = 0; ni < 4; ni++) {
    int n = bn * 64 + ni * 16 + ml;
    float bv = bias[n];
#pragma unroll
    for (int mi = 0; mi < 2; mi++) {
      int m0 = bm * 128 + wave * 32 + mi * 16 + kg * 4;
#pragma unroll
      for (int r = 0; r < 4; r++)
        c_out[(size_t)(m0 + r) * 768 + n] = acc[mi][ni][r] + bv;
    }
  }
}

// ---------------- flash attention: 32x32x16 MFMA, register-only P ----------------
// Wave owns 32 q. S^T[64key][32q] = mfma32(K-frag, Q-frag) x (2 nt x 4 kc).
// S^T C/D: q = lane&31, key = 32*nt + (reg&3) + 8*(reg>>2) + 4*(lane>>5).
// PV B-operand wants lane-half h to hold keys 16ks+8h+j; assembled from packed
// exp2(S) pairs + shfl_xor(32) partner copies + per-half selects. No P in LDS.
// O^T[d][q]: q = lane&31 (in-lane epilogue), d = 32dt+8g+4h+r (float4 stores).
// XCD swizzle: id&7 -> xcd; 16 q-blocks of one bh stay on one XCD (K/V in L2).
__global__ __launch_bounds__(256, 3) void attn_kernel(
    const u16* __restrict__ qs, const u16* __restrict__ ks, const u16* __restrict__ vt,
    float* __restrict__ attn_f32, u16* __restrict__ attn_bf) {
  __shared__ __align__(16) u16 sK[2][4096];   // swizzled [key][dim]
  __shared__ __align__(16) u16 sV[2][4096];   // swizzled [dim][key] (from V^T)
  const int tid = threadIdx.x, lane = tid & 63, wave = tid >> 6;
  const int c31 = lane & 31, h = lane >> 5;

  int id = blockIdx.y * 16 + blockIdx.x;      // 768 blocks
  int xcd = id & 7, slot = id >> 3;           // slot 0..95
  int bh = xcd * 6 + (slot >> 4);             // 6 heads per XCD
  int qb = slot & 15;
  const int q0w = qb * 128 + wave * 32;
  const size_t base = (size_t)bh * 131072;

  bf16x8 qf[4];  // B-frags: lane holds Q[q=c31][d = kc*16 + h*8 + j]
#pragma unroll
  for (int kc = 0; kc < 4; kc++)
    qf[kc] = ld_frag(qs + base + (size_t)(q0w + c31) * 64 + kc * 16 + h * 8);

  f32x4 lacc = {};
  f32x16 O0 = {}, O1 = {};

  // A-frag read base: row c31(+32nt), phys chunk offset = kx8 ^ (16*kc)
  const int kx8 = ((h ^ (c31 & 7))) * 8;
  const u16* kR = &sK[0][c31 * 64];
  const u16* vR = &sV[0][c31 * 64];

  // staging: slot q=p*256+tid holds logical (r=q>>3, c=(q&7)^(r&7))
  const int r0 = tid >> 3,         c0 = (tid & 7) ^ (r0 & 7);
  const int r1 = (256 + tid) >> 3, c1 = (tid & 7) ^ (r1 & 7);
  const u16* kgp0 = ks + base + r0 * 64 + c0 * 8;    // + kt*64
  const u16* kgp1 = ks + base + r1 * 64 + c1 * 8;
  const u16* vgp0 = vt + base + r0 * 2048 + c0 * 8;  // + kt
  const u16* vgp1 = vt + base + r1 * 2048 + c1 * 8;

  auto stage = [&](int b, int kt) {
    gld16(kgp0 + kt * 64, &sK[b][tid * 8]);
    gld16(kgp1 + kt * 64, &sK[b][2048 + tid * 8]);
    gld16(vgp0 + kt,      &sV[b][tid * 8]);
    gld16(vgp1 + kt,      &sV[b][2048 + tid * 8]);
  };

  stage(0, 0);
  for (int kt = 0; kt < 2048; kt += 128) {
#pragma unroll
    for (int half = 0; half < 2; half++) {   // buf index compile-time
      const int cur = kt + half * 64;
      __syncthreads();  // current buf DMA complete; prev reads done
      if (cur + 64 < 2048) stage(half ^ 1, cur + 64);

      // ---- S^T = K Q^T (log2-units; Q pre-scaled by log2e/8) ----
      f32x16 S0 = {}, S1 = {};
#pragma unroll
      for (int kc = 0; kc < 4; kc++) {
        const u16* kp = kR + half * 4096 + (kx8 ^ (kc * 16));
        S0 = MF32(ld_frag(kp),        qf[kc], S0);
        S1 = MF32(ld_frag(kp + 2048), qf[kc], S1);
      }

      // ---- p = exp2(s); accumulate l; pack pairs ----
      uint32_t w[2][8], x[2][8];
#pragma unroll
      for (int nt = 0; nt < 2; nt++) {
        const f32x16& S = nt ? S1 : S0;
#pragma unroll
        for (int g = 0; g < 4; g++) {
          float p0 = __builtin_amdgcn_exp2f(S[4 * g + 0]);
          float p1 = __builtin_amdgcn_exp2f(S[4 * g + 1]);
          float p2 = __builtin_amdgcn_exp2f(S[4 * g + 2]);
          float p3 = __builtin_amdgcn_exp2f(S[4 * g + 3]);
          lacc[0] += p0; lacc[1] += p1; lacc[2] += p2; lacc[3] += p3;
          w[nt][2 * g]     = pk_bf16(p0, p1);
          w[nt][2 * g + 1] = pk_bf16(p2, p3);
        }
      }
      // partner half copies (lane^32)
#pragma unroll
      for (int nt = 0; nt < 2; nt++)
#pragma unroll
        for (int i = 0; i < 8; i++)
          x[nt][i] = (uint32_t)__shfl_xor((int)w[nt][i], 32);

      // ---- O^T += V^T P^T (B-frags assembled per lane-half) ----
#pragma unroll
      for (int ksi = 0; ksi < 4; ksi++) {
        int nt = ksi >> 1, s4 = (ksi & 1) * 4;
        uint32_t b0 = h ? x[nt][s4 + 2] : w[nt][s4 + 0];
        uint32_t b1 = h ? x[nt][s4 + 3] : w[nt][s4 + 1];
        uint32_t b2 = h ? w[nt][s4 + 2] : x[nt][s4 + 0];
        uint32_t b3 = h ? w[nt][s4 + 3] : x[nt][s4 + 1];
        uint4 ub = {b0, b1, b2, b3};
        bf16x8 pf = __builtin_bit_cast(bf16x8, ub);
        const u16* vp = vR + half * 4096 + (kx8 ^ (ksi * 16));
        O0 = MF32(ld_frag(vp),        pf, O0);
        O1 = MF32(ld_frag(vp + 2048), pf, O1);
      }
    }
  }

  // ---- epilogue: fully in-lane (q = q0w + c31) ----
  float l = lacc[0] + lacc[1] + lacc[2] + lacc[3];
  l += __shfl_xor(l, 32);
  float inv = __builtin_amdgcn_rcpf(l);
  int b = bh / 12, hh = bh - b * 12;
  size_t rowoff = ((size_t)(b * 2048 + q0w + c31)) * 768 + hh * 64;
#pragma unroll
  for (int dt = 0; dt < 2; dt++) {
    const f32x16& Ot = dt ? O1 : O0;
#pragma unroll
    for (int g = 0; g < 4; g++) {
      int d0 = dt * 32 + g * 8 + h * 4;
      float4 o4 = {Ot[4 * g + 0] * inv, Ot[4 * g + 1] * inv,
                   Ot[4 * g + 2] * inv, Ot[4 * g + 3] * inv};
      *(float4*)(attn_f32 + rowoff + d0) = o4;
      uint2 wv;
      wv.x = pk_bf16(o4.x, o4.y);
      wv.y = pk_bf16(o4.z, o4.w);
      *(uint2*)(attn_bf + rowoff + d0) = wv;
    }
  }
}

extern "C" void kernel_launch(void* const* d_in, const int* in_sizes, int n_in,
                              void* d_out, int out_size, void* d_ws, size_t ws_size,
                              hipStream_t stream) {
  const float* x      = (const float*)d_in[0];
  const float* W_qkv  = (const float*)d_in[1];
  const float* b_qkv  = (const float*)d_in[2];
  const float* W_proj = (const float*)d_in[3];
  const float* b_proj = (const float*)d_in[4];
  float* out      = (float*)d_out;                  // [8192,768]
  float* attn_out = out + (size_t)8192 * 768;       // [8192,768]

  char* ws = (char*)d_ws;
  const size_t SZ_XB = (size_t)8192 * 768 * 2;      // 12.58 MB
  u16* xb      = (u16*)(ws);                         // reused as bf16 attn_out for proj
  u16* wqkv_t  = (u16*)(ws + SZ_XB);
  u16* wproj_t = (u16*)(ws + SZ_XB + 3538944);
  u16* qs      = (u16*)(ws + SZ_XB + 3538944 + 1179648);
  u16* ks      = (u16*)((char*)qs + SZ_XB);
  u16* vt      = (u16*)((char*)ks + SZ_XB);          // V^T [B,H,D,N]
  u16* ab      = xb;

  prep_kernel<<<6144 + 1728 + 576, 256, 0, stream>>>(x, xb, W_qkv, wqkv_t, W_proj, wproj_t);
  gemm_qkv<<<dim3(18, 64), 256, 0, stream>>>(xb, wqkv_t, b_qkv, qs, ks, vt);
  attn_kernel<<<dim3(16, 48), 256, 0, stream>>>(qs, ks, vt, attn_out, ab);
  gemm_proj<<<dim3(12, 64), 256, 0, stream>>>(ab, wproj_t, b_proj, out);
}